// Round 12
// baseline (190.601 us; speedup 1.0000x reference)
//
#include <hip/hip_runtime.h>
#include <hip/hip_bf16.h>

#define NPG 100     // nodes per graph
#define HF 64       // hidden width
#define ST 72       // Trm row stride (bf16): 64 + 8 pad (row*144B, 16B-aligned)
#define SAT 120     // Tc row stride (bf16): 112 k-cols + 8 pad (row*240B, 16B-aligned)
#define CMW 28      // count-matrix words per row (112 u8 cols)

typedef float  f4   __attribute__((ext_vector_type(4)));
typedef float  f16v __attribute__((ext_vector_type(16)));
typedef short  bf8  __attribute__((ext_vector_type(8)));

#define SZ_TC  (HF * SAT * 2)         // 15360
#define SZ_TRM (128 * ST * 2)         // 18432
#define OFF_TCA 0
#define OFF_TCB SZ_TC                 // 15360
#define OFF_TRM (2 * SZ_TC)           // 30720
#define OFF_CM  0                     // u8 counts [128][28 u32] = 14336, overlays TcA (setup)
#define OFF_MISC (OFF_TRM + SZ_TRM)   // 49152
#define SMEM_BYTES (OFF_MISC + 1280)  // 50432 -> 3 blocks/CU if VGPR allows 12 waves

// bf16 weight workspace (d_ws), layout Wt[k5][fo][fi]:
//   W1t [5][64][16] @ 0  (fi zero-padded 3->16)
//   W2t [5][64][64] @ 5120
//   W3t [5][64][64] @ 25600
#define WT_TOTAL 46080

__device__ __forceinline__ unsigned short f2bf(float f) {
    unsigned u = __float_as_uint(f);
    u += 0x7fffu + ((u >> 16) & 1u);   // round-to-nearest-even
    return (unsigned short)(u >> 16);
}
// packed 2xf32 -> bf16x2 (v_cvt_pk_bf16_f32, RNE — same rounding as f2bf)
__device__ __forceinline__ unsigned pk2bf(float a, float b) {
    float2 f2; f2.x = a; f2.y = b;
    __hip_bfloat162 h2 = __float22bfloat162_rn(f2);
    return *reinterpret_cast<unsigned*>(&h2);
}
__device__ __forceinline__ f16v zerov16() {
    f16v z;
    #pragma unroll
    for (int i = 0; i < 16; i++) z[i] = 0.f;
    return z;
}

__global__ void wconv(const float* __restrict__ W1, const float* __restrict__ W2,
                      const float* __restrict__ W3, unsigned short* __restrict__ ws)
{
    int idx = blockIdx.x * 256 + threadIdx.x;
    if (idx >= WT_TOTAL) return;
    float v;
    if (idx < 5120) {
        int k5 = idx >> 10, rem = idx & 1023, fo = rem >> 4, fi = rem & 15;
        v = (fi < 3) ? W1[(k5 * 3 + fi) * HF + fo] : 0.f;
    } else if (idx < 25600) {
        int j = idx - 5120;
        int k5 = j >> 12, rem = j & 4095, fo = rem >> 6, fi = rem & 63;
        v = W2[(k5 * HF + fi) * HF + fo];
    } else {
        int j = idx - 25600;
        int k5 = j >> 12, rem = j & 4095, fo = rem >> 6, fi = rem & 63;
        v = W3[(k5 * HF + fi) * HF + fo];
    }
    ws[idx] = f2bf(v);
}

// One block per graph, 256 threads = 4 waves.
// NEW ownership: wave wg owns np-tile wg (rows 32wg..+31) x ALL 64 features.
//  -> TW is fully wave-local (A = own Trm rows, self-written): no barrier, and
//     it issues BEFORE the stage barrier (overlaps other waves' skew).
//  -> Tc is PING-PONGED (A/B): one barrier per stage (none at s=4); dst buffer
//     naturally holds T_{s-2} -> Chebyshev old term is a b64 readback (no
//     prev/oldr registers at all).
// LHAT: C[np][fo] = sum_n Ahat[np][n]*T[n][fo]; A = af regs (own rows, 28 VGPR),
//       B = Tc rows b128. Two fo-tiles processed sequentially (caps VGPRs).
// TW:   O[np][fo] += sum_fi T[np][fi]*Wt[fo][fi]; A = own Trm rows b128
//       (shared across both fo-tiles), B = Wt b128 global.
// C/D: col = lane&31, row = (r&3)+8*(r>>2)+4*(lane>>5).
// (256,1): VGPR-cap lore (R3/R6/R9/R10) — min-waves m caps VGPRs at ~256/m;
// m=1 guarantees no spill. LDS 50432 -> 3 blocks/CU when VGPRs permit.
__launch_bounds__(256, 1)
__global__ void chebsw(const float* __restrict__ x, const int* __restrict__ ei,
                       const float* __restrict__ lambda_max,
                       const unsigned short* __restrict__ Wt,
                       const float* __restrict__ b1, const float* __restrict__ b2,
                       const float* __restrict__ b3,
                       const float* __restrict__ bng, const float* __restrict__ bnb,
                       const float* __restrict__ bnm, const float* __restrict__ bnv,
                       const float* __restrict__ fc1w, const float* __restrict__ fc1b,
                       const float* __restrict__ fc2w, const float* __restrict__ fc2b,
                       float* __restrict__ out, int E_total, int epg)
{
    extern __shared__ char sm[];
    const int tid = threadIdx.x;
    const int g = blockIdx.x;
    const int ebase = g * epg, nbase = g * NPG;
    const int wg = tid >> 6, lane = tid & 63;
    const int l31 = lane & 31, hh = lane >> 5;

    unsigned* Cm  = (unsigned*)(sm + OFF_CM);
    float* dis    = (float*)(sm + OFF_MISC);          // 448 B (112 entries)
    float* pool   = (float*)(sm + OFF_MISC + 448);    // 256 B
    float* gvn    = (float*)(sm + OFF_MISC + 704);    // 256 B
    float* zf     = (float*)(sm + OFF_MISC + 960);    // 128 B
    float* logits = (float*)(sm + OFF_MISC + 1088);   // 64 B
    float* lsep   = (float*)(sm + OFF_MISC + 1152);

    const float lam = lambda_max[g];
    const float two_l = 2.0f / lam;
    const float cl = two_l - 1.0f;

    // ---------------- u8 count matrix + dis ----------------
    for (int i = tid; i < (128 * CMW) / 4; i += 256)
        ((f4*)Cm)[i] = (f4){0.f, 0.f, 0.f, 0.f};
    __syncthreads();
    for (int e = tid; e < epg; e += 256) {
        int r = ei[ebase + e] - nbase;
        int c = ei[E_total + ebase + e] - nbase;
        atomicAdd(&Cm[r * CMW + (c >> 2)], 1u << (8 * (c & 3)));
    }
    __syncthreads();
    if (tid < 112) {
        float dv = 0.f;
        if (tid < NPG) {
            unsigned s = 0;
            #pragma unroll
            for (int w = 0; w < CMW; w++) {
                unsigned u = Cm[tid * CMW + w];
                s += (u & 255) + ((u >> 8) & 255) + ((u >> 16) & 255) + (u >> 24);
            }
            dv = s > 0 ? rsqrtf((float)s) : 0.f;
        }
        dis[tid] = dv;
    }
    __syncthreads();

    // ---------------- A-hat fragments -> registers (own np-tile only) ----------------
    bf8 af[7];
    {
        int rr = 32 * wg + l31;
        bool rv = (rr < NPG);
        float base = rv ? (-two_l * dis[rr]) : 0.f;
        #pragma unroll
        for (int Ks = 0; Ks < 7; Ks++) {
            int k0 = Ks * 16 + 8 * hh;
            unsigned w0 = rv ? Cm[rr * CMW + (k0 >> 2)]     : 0u;
            unsigned w1 = rv ? Cm[rr * CMW + (k0 >> 2) + 1] : 0u;
            unsigned up[4];
            #pragma unroll
            for (int jj = 0; jj < 4; jj++) {
                int ka = k0 + 2 * jj, kb = ka + 1;
                unsigned wa = (jj < 2) ? w0 : w1;
                float va = base * (float)((wa >> (8 * (ka & 3))) & 255u) * dis[ka];
                float vb = base * (float)((wa >> (8 * (kb & 3))) & 255u) * dis[kb];
                if (rv && ka == rr) va += cl;
                if (rv && kb == rr) vb += cl;
                up[jj] = pk2bf(va, vb);
            }
            af[Ks] = *reinterpret_cast<bf8*>(up);
        }
    }
    __syncthreads();   // Cm reads done before TcA (overlay) is zeroed

    // ---------------- init TcA+TcB+Trm: zero + x ----------------
    for (int i = tid; i < (2 * SZ_TC + SZ_TRM) / 16; i += 256)
        ((f4*)sm)[i] = (f4){0.f, 0.f, 0.f, 0.f};
    if (tid < HF) pool[tid] = 0.f;
    __syncthreads();
    if (tid < NPG) {
        unsigned short h0 = f2bf(x[(nbase + tid) * 3 + 0]);
        unsigned short h1 = f2bf(x[(nbase + tid) * 3 + 1]);
        unsigned short h2 = f2bf(x[(nbase + tid) * 3 + 2]);
        *(unsigned*)(sm + OFF_TRM + (tid * ST) * 2) = (unsigned)h0 | ((unsigned)h1 << 16);
        *(unsigned short*)(sm + OFF_TRM + (tid * ST + 2) * 2) = h2;
        *(unsigned short*)(sm + OFF_TCA + (0 * SAT + tid) * 2) = h0;
        *(unsigned short*)(sm + OFF_TCA + (1 * SAT + tid) * 2) = h1;
        *(unsigned short*)(sm + OFF_TCA + (2 * SAT + tid) * 2) = h2;
    }
    __syncthreads();

    // ---------------- 3 ChebConv layers ----------------
    f16v acc[2];
    const float* bsv[3] = {b1, b2, b3};
    const int arow = (32 * wg + l31) * ST;   // own Trm row (TW A-op)

    for (int L = 0; L < 3; L++) {
        const bool l1 = (L == 0);
        const unsigned short* Wl = l1 ? Wt : (Wt + (L == 1 ? 5120 : 25600));
        acc[0] = zerov16();
        acc[1] = zerov16();

        auto TW = [&](int k5) {
            const int nKs = l1 ? 1 : 4;
            for (int Ks = 0; Ks < nKs; Ks++) {
                bf8 a = *(const bf8*)(sm + OFF_TRM + (arow + Ks * 16 + 8 * hh) * 2);
                #pragma unroll
                for (int t = 0; t < 2; t++) {
                    bf8 bw;
                    if (l1) bw = *(const bf8*)(Wl + (k5 * 64 + 32 * t + l31) * 16 + 8 * hh);
                    else    bw = *(const bf8*)(Wl + (k5 * 64 + 32 * t + l31) * 64 + Ks * 16 + 8 * hh);
                    acc[t] = __builtin_amdgcn_mfma_f32_32x32x16_bf16(a, bw, acc[t], 0, 0, 0);
                }
            }
        };

        TW(0);
        int srcO = OFF_TCA, dstO = OFF_TCB;
        #pragma unroll
        for (int s = 1; s <= 4; s++) {
            #pragma unroll
            for (int t = 0; t < 2; t++) {     // fo-tiles sequential (caps VGPRs)
                const int frow = (32 * t + l31) * SAT;
                bf8 bfr[7];
                #pragma unroll
                for (int Ks = 0; Ks < 7; Ks++)
                    bfr[Ks] = *(const bf8*)(sm + srcO + (frow + Ks * 16 + 8 * hh) * 2);
                f16v c = zerov16();
                #pragma unroll
                for (int Ks = 0; Ks < 7; Ks++)
                    c = __builtin_amdgcn_mfma_f32_32x32x16_bf16(af[Ks], bfr[Ks], c, 0, 0, 0);
                unsigned hp[8];
                #pragma unroll
                for (int q4 = 0; q4 < 4; q4++) {
                    int np0 = 32 * wg + 8 * q4 + 4 * hh;
                    bool wv = (np0 < NPG);
                    uint2 old;
                    old.x = 0u; old.y = 0u;
                    if (s >= 2 && wv)   // dst buffer holds T_{s-2} at these cells
                        old = *(const uint2*)(sm + dstO + (frow + np0) * 2);
                    #pragma unroll
                    for (int pp = 0; pp < 2; pp++) {
                        int p = 2 * q4 + pp;
                        unsigned ow = pp ? old.y : old.x;
                        float c0 = c[2 * p], c1 = c[2 * p + 1];
                        if (s >= 2) {
                            c0 = 2.f * c0 - __uint_as_float(ow << 16);
                            c1 = 2.f * c1 - __uint_as_float(ow & 0xffff0000u);
                        }
                        hp[p] = pk2bf(c0, c1);
                    }
                    if (s < 4 && wv) {        // T4's Tc never read -> skip
                        uint2 pk;
                        pk.x = hp[2 * q4];
                        pk.y = hp[2 * q4 + 1];
                        *(uint2*)(sm + dstO + (frow + np0) * 2) = pk;
                    }
                }
                // Trm writes: own rows, col fo_t (scalar b16, guarded)
                #pragma unroll
                for (int r = 0; r < 16; r++) {
                    int np = 32 * wg + (r & 3) + 8 * (r >> 2) + 4 * hh;
                    if (np < NPG) {
                        unsigned short hv = (r & 1) ? (unsigned short)(hp[r >> 1] >> 16)
                                                    : (unsigned short)(hp[r >> 1] & 0xffffu);
                        *(unsigned short*)(sm + OFF_TRM + (np * ST + 32 * t + l31) * 2) = hv;
                    }
                }
            }
            TW(s);             // wave-local: reads only own (just-written) Trm rows
            if (s < 4) __syncthreads();   // publish T_s Tc; s=4 wrote no Tc
            int tmp = srcO; srcO = dstO; dstO = tmp;
        }

        if (L < 2) {
            // epilogue: h = relu(acc+b) -> TcA + Trm. TcA cells last cross-wave
            // read at s=3 (barrier passed); s=4's old-reads were own cells.
            #pragma unroll
            for (int t = 0; t < 2; t++) {
                const float bias = bsv[L][32 * t + l31];
                const int frow = (32 * t + l31) * SAT;
                unsigned hp[8];
                #pragma unroll
                for (int p = 0; p < 8; p++) {
                    float v0 = fmaxf(acc[t][2 * p]     + bias, 0.f);
                    float v1 = fmaxf(acc[t][2 * p + 1] + bias, 0.f);
                    hp[p] = pk2bf(v0, v1);
                }
                #pragma unroll
                for (int q4 = 0; q4 < 4; q4++) {
                    int np0 = 32 * wg + 8 * q4 + 4 * hh;
                    if (np0 < NPG) {
                        uint2 pk;
                        pk.x = hp[2 * q4];
                        pk.y = hp[2 * q4 + 1];
                        *(uint2*)(sm + OFF_TCA + (frow + np0) * 2) = pk;
                    }
                }
                #pragma unroll
                for (int r = 0; r < 16; r++) {
                    int np = 32 * wg + (r & 3) + 8 * (r >> 2) + 4 * hh;
                    if (np < NPG) {
                        unsigned short hv = (r & 1) ? (unsigned short)(hp[r >> 1] >> 16)
                                                    : (unsigned short)(hp[r >> 1] & 0xffffu);
                        *(unsigned short*)(sm + OFF_TRM + (np * ST + 32 * t + l31) * 2) = hv;
                    }
                }
            }
            __syncthreads();   // next layer's T0 (TcA) visible to all waves
        } else {
            // mean pool from acc regs
            #pragma unroll
            for (int t = 0; t < 2; t++) {
                const float bias = bsv[L][32 * t + l31];
                float ssum = 0.f;
                #pragma unroll
                for (int r = 0; r < 16; r++) {
                    int np = 32 * wg + (r & 3) + 8 * (r >> 2) + 4 * hh;
                    float h = fmaxf(acc[t][r] + bias, 0.f);
                    if (np < NPG) ssum += h;
                }
                ssum += __shfl_xor(ssum, 32, 64);
                if (hh == 0) atomicAdd(&pool[32 * t + l31], ssum);
            }
            __syncthreads();
        }
    }

    // ---------------- BN + MLP + log_softmax ----------------
    if (tid < HF) {
        float gv = pool[tid] * (1.0f / NPG);
        gv = (gv - bnm[tid]) * rsqrtf(bnv[tid] + 1e-5f) * bng[tid] + bnb[tid];
        gvn[tid] = gv;
    }
    __syncthreads();
    if (tid < 32) {
        float a = fc1b[tid];
        for (int f = 0; f < HF; f++) a += gvn[f] * fc1w[f * 32 + tid];
        zf[tid] = fmaxf(a, 0.f);
    }
    __syncthreads();
    if (tid < 10) {
        float a = fc2b[tid];
        for (int k = 0; k < 32; k++) a += zf[k] * fc2w[k * 10 + tid];
        logits[tid] = a;
    }
    __syncthreads();
    if (tid == 0) {
        float m = logits[0];
        for (int i = 1; i < 10; i++) m = fmaxf(m, logits[i]);
        float s = 0.f;
        for (int i = 0; i < 10; i++) s += expf(logits[i] - m);
        lsep[0] = m + logf(s);
    }
    __syncthreads();
    if (tid < 10) out[g * 10 + tid] = logits[tid] - lsep[0];
}

extern "C" void kernel_launch(void* const* d_in, const int* in_sizes, int n_in,
                              void* d_out, int out_size, void* d_ws, size_t ws_size,
                              hipStream_t stream) {
    const float* x    = (const float*)d_in[0];
    const int*   ei   = (const int*)d_in[1];
    const float* lmax = (const float*)d_in[3];
    const float* W1   = (const float*)d_in[4];
    const float* b1   = (const float*)d_in[5];
    const float* W2   = (const float*)d_in[6];
    const float* b2   = (const float*)d_in[7];
    const float* W3   = (const float*)d_in[8];
    const float* b3   = (const float*)d_in[9];
    const float* bng  = (const float*)d_in[10];
    const float* bnb  = (const float*)d_in[11];
    const float* bnm  = (const float*)d_in[12];
    const float* bnv  = (const float*)d_in[13];
    const float* fc1w = (const float*)d_in[14];
    const float* fc1b = (const float*)d_in[15];
    const float* fc2w = (const float*)d_in[16];
    const float* fc2b = (const float*)d_in[17];

    const int E = in_sizes[1] / 2;
    const int G = in_sizes[3];
    const int epg = E / G;

    unsigned short* Wt = (unsigned short*)d_ws;

    wconv<<<(WT_TOTAL + 255) / 256, 256, 0, stream>>>(W1, W2, W3, Wt);

    hipFuncSetAttribute((const void*)chebsw,
                        hipFuncAttributeMaxDynamicSharedMemorySize, SMEM_BYTES);

    chebsw<<<G, 256, SMEM_BYTES, stream>>>(x, ei, lmax, Wt, b1, b2, b3,
                                           bng, bnb, bnm, bnv, fc1w, fc1b, fc2w, fc2b,
                                           (float*)d_out, E, epg);
}

// Round 13
// 190.529 us; speedup vs baseline: 1.0004x; 1.0004x over previous
//
#include <hip/hip_runtime.h>
#include <hip/hip_bf16.h>

#define NPG 100     // nodes per graph
#define HF 64       // hidden width
#define NROW 128    // node rows padded to 4 x 32 tiles
#define ST 72       // Trm row stride (bf16): 64 + 8 pad
#define SAT 136     // Tc row stride (bf16): 128 + 8 pad
#define CMW 28      // count-matrix words per row (112 u8 cols)

typedef float  f4   __attribute__((ext_vector_type(4)));
typedef float  f16v __attribute__((ext_vector_type(16)));
typedef short  bf8  __attribute__((ext_vector_type(8)));

#define SZ_TC  (HF * SAT * 2)         // 17408
#define SZ_TRM (NROW * ST * 2)        // 18432
#define OFF_TC  0
#define OFF_TRM SZ_TC                 // 17408
#define OFF_CM  0                     // u8 counts [128][28 u32] = 14336, overlays Tc (setup)
#define OFF_MISC (OFF_TRM + SZ_TRM)   // 35840
#define SMEM_BYTES (OFF_MISC + 1280)  // 37120

// bf16 weight workspace (d_ws), layout Wt[k5][fo][fi]:
//   W1t [5][64][16] @ 0  (fi zero-padded 3->16)
//   W2t [5][64][64] @ 5120
//   W3t [5][64][64] @ 25600
#define WT_TOTAL 46080

__device__ __forceinline__ unsigned short f2bf(float f) {
    unsigned u = __float_as_uint(f);
    u += 0x7fffu + ((u >> 16) & 1u);   // round-to-nearest-even
    return (unsigned short)(u >> 16);
}
// packed 2xf32 -> bf16x2 (v_cvt_pk_bf16_f32, RNE — same rounding as f2bf)
__device__ __forceinline__ unsigned pk2bf(float a, float b) {
    float2 f2; f2.x = a; f2.y = b;
    __hip_bfloat162 h2 = __float22bfloat162_rn(f2);
    return *reinterpret_cast<unsigned*>(&h2);
}
__device__ __forceinline__ f16v zerov16() {
    f16v z;
    #pragma unroll
    for (int i = 0; i < 16; i++) z[i] = 0.f;
    return z;
}

__global__ void wconv(const float* __restrict__ W1, const float* __restrict__ W2,
                      const float* __restrict__ W3, unsigned short* __restrict__ ws)
{
    int idx = blockIdx.x * 256 + threadIdx.x;
    if (idx >= WT_TOTAL) return;
    float v;
    if (idx < 5120) {
        int k5 = idx >> 10, rem = idx & 1023, fo = rem >> 4, fi = rem & 15;
        v = (fi < 3) ? W1[(k5 * 3 + fi) * HF + fo] : 0.f;
    } else if (idx < 25600) {
        int j = idx - 5120;
        int k5 = j >> 12, rem = j & 4095, fo = rem >> 6, fi = rem & 63;
        v = W2[(k5 * HF + fi) * HF + fo];
    } else {
        int j = idx - 25600;
        int k5 = j >> 12, rem = j & 4095, fo = rem >> 6, fi = rem & 63;
        v = W3[(k5 * HF + fi) * HF + fo];
    }
    ws[idx] = f2bf(v);
}

// One block per graph, 256 threads = 4 waves. R11 body (87-91 us class) with
// ROLLED outer loops: layer loop (3x) and stage loop (4x) are unroll(disable)
// -> hot text ~12x smaller, fits 32 KB L1I. Theory: all prior variants were
// I$-bound (every pipe <30%, wall invariant under data-path changes).
// Register-array-indexed inner loops stay unrolled (rolling would spill).
// A-hat fragments in registers (af[2][7], built once from u8 count matrix).
// Single in-place dual-orientation T: Tc = T^T (LHAT B b128), Trm (TW A b128).
// LHAT: C[np][fo] = sum_n Ahat[np][n] * T[n][fo]  (A=af regs, B=Tc rows b128)
// TW:   O[np][fo] += sum_fi T[np][fi] * Wt[fo][fi] (A=Trm rows b128, B=Wt b128)
// C/D: col = lane&31, row = (r&3)+8*(r>>2)+4*(lane>>5)
// Cheb prev/old in packed-bf16 regs; packed-domain cheb update.
// (256,2): VGPR cap 128 (R3/R6/R9/R10 lore: cap ~256/min_waves).
__launch_bounds__(256, 2)
__global__ void chebrl(const float* __restrict__ x, const int* __restrict__ ei,
                       const float* __restrict__ lambda_max,
                       const unsigned short* __restrict__ Wt,
                       const float* __restrict__ b1, const float* __restrict__ b2,
                       const float* __restrict__ b3,
                       const float* __restrict__ bng, const float* __restrict__ bnb,
                       const float* __restrict__ bnm, const float* __restrict__ bnv,
                       const float* __restrict__ fc1w, const float* __restrict__ fc1b,
                       const float* __restrict__ fc2w, const float* __restrict__ fc2b,
                       float* __restrict__ out, int E_total, int epg)
{
    extern __shared__ char sm[];
    const int tid = threadIdx.x;
    const int g = blockIdx.x;
    const int ebase = g * epg, nbase = g * NPG;
    const int wg = tid >> 6, lane = tid & 63;
    const int l31 = lane & 31, hh = lane >> 5;
    const int ht  = wg & 1;          // f-tile: cols 32*ht..+31
    const int Mt0 = (wg >> 1) * 2;   // n'-tile pair base
    const int fo  = ht * 32 + l31;

    unsigned* Cm  = (unsigned*)(sm + OFF_CM);
    float* dis    = (float*)(sm + OFF_MISC);          // 448 B (112 entries)
    float* pool   = (float*)(sm + OFF_MISC + 448);    // 256 B
    float* gvn    = (float*)(sm + OFF_MISC + 704);    // 256 B
    float* zf     = (float*)(sm + OFF_MISC + 960);    // 128 B
    float* logits = (float*)(sm + OFF_MISC + 1088);   // 64 B
    float* lsep   = (float*)(sm + OFF_MISC + 1152);

    const float lam = lambda_max[g];
    const float two_l = 2.0f / lam;
    const float cl = two_l - 1.0f;

    // ---------------- u8 count matrix + dis ----------------
    #pragma clang loop unroll(disable)
    for (int i = tid; i < (NROW * CMW) / 4; i += 256)
        ((f4*)Cm)[i] = (f4){0.f, 0.f, 0.f, 0.f};
    __syncthreads();
    #pragma clang loop unroll(disable)
    for (int e = tid; e < epg; e += 256) {
        int r = ei[ebase + e] - nbase;
        int c = ei[E_total + ebase + e] - nbase;
        atomicAdd(&Cm[r * CMW + (c >> 2)], 1u << (8 * (c & 3)));
    }
    __syncthreads();
    if (tid < 112) {
        float dv = 0.f;
        if (tid < NPG) {
            unsigned s = 0;
            #pragma clang loop unroll(disable)
            for (int w = 0; w < CMW; w++) {
                unsigned u = Cm[tid * CMW + w];
                s += (u & 255) + ((u >> 8) & 255) + ((u >> 16) & 255) + (u >> 24);
            }
            dv = s > 0 ? rsqrtf((float)s) : 0.f;
        }
        dis[tid] = dv;
    }
    __syncthreads();

    // ---------------- A-hat fragments -> registers (once) ----------------
    bf8 af[2][7];
    #pragma unroll
    for (int m = 0; m < 2; m++) {
        int rr = 32 * (Mt0 + m) + l31;
        bool rv = (rr < NPG);
        float base = rv ? (-two_l * dis[rr]) : 0.f;
        #pragma unroll
        for (int Ks = 0; Ks < 7; Ks++) {
            int k0 = Ks * 16 + 8 * hh;
            unsigned w0 = rv ? Cm[rr * CMW + (k0 >> 2)]     : 0u;
            unsigned w1 = rv ? Cm[rr * CMW + (k0 >> 2) + 1] : 0u;
            unsigned up[4];
            #pragma unroll
            for (int jj = 0; jj < 4; jj++) {
                int ka = k0 + 2 * jj, kb = ka + 1;
                unsigned wa = (jj < 2) ? w0 : w1;
                float va = base * (float)((wa >> (8 * (ka & 3))) & 255u) * dis[ka];
                float vb = base * (float)((wa >> (8 * (kb & 3))) & 255u) * dis[kb];
                if (rv && ka == rr) va += cl;
                if (rv && kb == rr) vb += cl;
                up[jj] = pk2bf(va, vb);
            }
            af[m][Ks] = *reinterpret_cast<bf8*>(up);
        }
    }
    __syncthreads();   // Cm reads done before Tc (overlay) is zeroed

    // ---------------- init Tc + Trm: zero + x ----------------
    #pragma clang loop unroll(disable)
    for (int i = tid; i < (SZ_TC + SZ_TRM) / 16; i += 256)
        ((f4*)sm)[i] = (f4){0.f, 0.f, 0.f, 0.f};
    if (tid < HF) pool[tid] = 0.f;
    __syncthreads();
    if (tid < NPG) {
        unsigned short h0 = f2bf(x[(nbase + tid) * 3 + 0]);
        unsigned short h1 = f2bf(x[(nbase + tid) * 3 + 1]);
        unsigned short h2 = f2bf(x[(nbase + tid) * 3 + 2]);
        *(unsigned*)(sm + OFF_TRM + (tid * ST) * 2) = (unsigned)h0 | ((unsigned)h1 << 16);
        *(unsigned short*)(sm + OFF_TRM + (tid * ST + 2) * 2) = h2;
        *(unsigned short*)(sm + OFF_TC + (0 * SAT + tid) * 2) = h0;
        *(unsigned short*)(sm + OFF_TC + (1 * SAT + tid) * 2) = h1;
        *(unsigned short*)(sm + OFF_TC + (2 * SAT + tid) * 2) = h2;
    }
    __syncthreads();

    // ---------------- 3 ChebConv layers (ROLLED) ----------------
    f16v acc[2];
    unsigned prev[2][8], oldr[2][8];

    // prev = x (layer 0 T0) at C-layout lane positions
    #pragma unroll
    for (int m = 0; m < 2; m++) {
        unsigned short tv[16];
        #pragma unroll
        for (int r = 0; r < 16; r++) {
            int np = (Mt0 + m) * 32 + (r & 3) + 8 * (r >> 2) + 4 * hh;
            tv[r] = *(const unsigned short*)(sm + OFF_TRM + (np * ST + fo) * 2);
        }
        #pragma unroll
        for (int p = 0; p < 8; p++)
            prev[m][p] = (unsigned)tv[2 * p] | ((unsigned)tv[2 * p + 1] << 16);
    }

    #pragma clang loop unroll(disable)
    for (int L = 0; L < 3; L++) {
        const bool l1 = (L == 0);
        const unsigned short* Wl = l1 ? Wt : (Wt + (L == 1 ? 5120 : 25600));
        const float* bg = l1 ? b1 : (L == 1 ? b2 : b3);
        acc[0] = zerov16();
        acc[1] = zerov16();

        auto TW = [&](int k5) {
            const int nKs = l1 ? 1 : 4;
            #pragma clang loop unroll(disable)
            for (int Ks = 0; Ks < nKs; Ks++) {
                bf8 bw;
                if (l1) bw = *(const bf8*)(Wl + (k5 * 64 + fo) * 16 + 8 * hh);
                else    bw = *(const bf8*)(Wl + (k5 * 64 + fo) * 64 + Ks * 16 + 8 * hh);
                #pragma unroll
                for (int m = 0; m < 2; m++) {
                    bf8 a = *(const bf8*)(sm + OFF_TRM +
                              (((Mt0 + m) * 32 + l31) * ST + Ks * 16 + 8 * hh) * 2);
                    acc[m] = __builtin_amdgcn_mfma_f32_32x32x16_bf16(a, bw, acc[m], 0, 0, 0);
                }
            }
        };

        TW(0);
        #pragma clang loop unroll(disable)
        for (int s = 1; s <= 4; s++) {
            bf8 bfr[7];
            #pragma unroll
            for (int Ks = 0; Ks < 7; Ks++)
                bfr[Ks] = *(const bf8*)(sm + OFF_TC + (fo * SAT + Ks * 16 + 8 * hh) * 2);
            __syncthreads();   // all T reads (TW(s-1), bfr) done before in-place writes
            #pragma unroll
            for (int m = 0; m < 2; m++) {
                f16v c = zerov16();
                #pragma unroll
                for (int Ks = 0; Ks < 7; Ks++)
                    c = __builtin_amdgcn_mfma_f32_32x32x16_bf16(af[m][Ks], bfr[Ks], c, 0, 0, 0);
                unsigned hp[8];
                #pragma unroll
                for (int p = 0; p < 8; p++) {
                    float c0 = c[2 * p], c1 = c[2 * p + 1];
                    if (s >= 2) {   // packed-domain cheb
                        c0 = 2.f * c0 - __uint_as_float(oldr[m][p] << 16);
                        c1 = 2.f * c1 - __uint_as_float(oldr[m][p] & 0xffff0000u);
                    }
                    hp[p] = pk2bf(c0, c1);
                    oldr[m][p] = prev[m][p];
                    prev[m][p] = hp[p];
                }
                if (s < 4) {       // T4's Tc is never read (epilogue rewrites Tc fully)
                    #pragma unroll
                    for (int q4 = 0; q4 < 4; q4++) {
                        int np0 = (Mt0 + m) * 32 + 8 * q4 + 4 * hh;
                        uint2 pk;
                        pk.x = hp[2 * q4];
                        pk.y = hp[2 * q4 + 1];
                        *(uint2*)(sm + OFF_TC + (fo * SAT + np0) * 2) = pk;
                    }
                }
                #pragma unroll
                for (int r = 0; r < 16; r++) {
                    int np = (Mt0 + m) * 32 + (r & 3) + 8 * (r >> 2) + 4 * hh;
                    unsigned short hv = (r & 1) ? (unsigned short)(hp[r >> 1] >> 16)
                                                : (unsigned short)(hp[r >> 1] & 0xffffu);
                    *(unsigned short*)(sm + OFF_TRM + (np * ST + fo) * 2) = hv;
                }
            }
            __syncthreads();   // writes visible before TW(s)
            TW(s);
        }
        __syncthreads();       // TW(4) reads done before epilogue writes

        const float bias = bg[fo];
        if (L < 2) {
            #pragma unroll
            for (int m = 0; m < 2; m++) {
                unsigned hp[8];
                #pragma unroll
                for (int p = 0; p < 8; p++) {
                    float v0 = fmaxf(acc[m][2 * p]     + bias, 0.f);
                    float v1 = fmaxf(acc[m][2 * p + 1] + bias, 0.f);
                    hp[p] = pk2bf(v0, v1);
                    prev[m][p] = hp[p];   // next layer's T0 carried in regs
                }
                #pragma unroll
                for (int q4 = 0; q4 < 4; q4++) {
                    int np0 = (Mt0 + m) * 32 + 8 * q4 + 4 * hh;
                    uint2 pk;
                    pk.x = hp[2 * q4];
                    pk.y = hp[2 * q4 + 1];
                    *(uint2*)(sm + OFF_TC + (fo * SAT + np0) * 2) = pk;
                }
                #pragma unroll
                for (int r = 0; r < 16; r++) {
                    int np = (Mt0 + m) * 32 + (r & 3) + 8 * (r >> 2) + 4 * hh;
                    unsigned short hv = (r & 1) ? (unsigned short)(hp[r >> 1] >> 16)
                                                : (unsigned short)(hp[r >> 1] & 0xffffu);
                    *(unsigned short*)(sm + OFF_TRM + (np * ST + fo) * 2) = hv;
                }
            }
            __syncthreads();
        } else {
            float ssum = 0.f;
            #pragma unroll
            for (int m = 0; m < 2; m++) {
                #pragma unroll
                for (int r = 0; r < 16; r++) {
                    int np = (Mt0 + m) * 32 + (r & 3) + 8 * (r >> 2) + 4 * hh;
                    float h = fmaxf(acc[m][r] + bias, 0.f);
                    if (np < NPG) ssum += h;
                }
            }
            ssum += __shfl_xor(ssum, 32, 64);
            if (hh == 0) atomicAdd(&pool[fo], ssum);
            __syncthreads();
        }
    }

    // ---------------- BN + MLP + log_softmax ----------------
    if (tid < HF) {
        float gv = pool[tid] * (1.0f / NPG);
        gv = (gv - bnm[tid]) * rsqrtf(bnv[tid] + 1e-5f) * bng[tid] + bnb[tid];
        gvn[tid] = gv;
    }
    __syncthreads();
    if (tid < 32) {
        float a = fc1b[tid];
        #pragma clang loop unroll(disable)
        for (int f = 0; f < HF; f++) a += gvn[f] * fc1w[f * 32 + tid];
        zf[tid] = fmaxf(a, 0.f);
    }
    __syncthreads();
    if (tid < 10) {
        float a = fc2b[tid];
        #pragma clang loop unroll(disable)
        for (int k = 0; k < 32; k++) a += zf[k] * fc2w[k * 10 + tid];
        logits[tid] = a;
    }
    __syncthreads();
    if (tid == 0) {
        float m = logits[0];
        for (int i = 1; i < 10; i++) m = fmaxf(m, logits[i]);
        float s = 0.f;
        for (int i = 0; i < 10; i++) s += expf(logits[i] - m);
        lsep[0] = m + logf(s);
    }
    __syncthreads();
    if (tid < 10) out[g * 10 + tid] = logits[tid] - lsep[0];
}

extern "C" void kernel_launch(void* const* d_in, const int* in_sizes, int n_in,
                              void* d_out, int out_size, void* d_ws, size_t ws_size,
                              hipStream_t stream) {
    const float* x    = (const float*)d_in[0];
    const int*   ei   = (const int*)d_in[1];
    const float* lmax = (const float*)d_in[3];
    const float* W1   = (const float*)d_in[4];
    const float* b1   = (const float*)d_in[5];
    const float* W2   = (const float*)d_in[6];
    const float* b2   = (const float*)d_in[7];
    const float* W3   = (const float*)d_in[8];
    const float* b3   = (const float*)d_in[9];
    const float* bng  = (const float*)d_in[10];
    const float* bnb  = (const float*)d_in[11];
    const float* bnm  = (const float*)d_in[12];
    const float* bnv  = (const float*)d_in[13];
    const float* fc1w = (const float*)d_in[14];
    const float* fc1b = (const float*)d_in[15];
    const float* fc2w = (const float*)d_in[16];
    const float* fc2b = (const float*)d_in[17];

    const int E = in_sizes[1] / 2;
    const int G = in_sizes[3];
    const int epg = E / G;

    unsigned short* Wt = (unsigned short*)d_ws;

    wconv<<<(WT_TOTAL + 255) / 256, 256, 0, stream>>>(W1, W2, W3, Wt);

    hipFuncSetAttribute((const void*)chebrl,
                        hipFuncAttributeMaxDynamicSharedMemorySize, SMEM_BYTES);

    chebrl<<<G, 256, SMEM_BYTES, stream>>>(x, ei, lmax, Wt, b1, b2, b3,
                                           bng, bnb, bnm, bnv, fc1w, fc1b, fc2w, fc2b,
                                           (float*)d_out, E, epg);
}